// Round 16
// baseline (331.816 us; speedup 1.0000x reference)
//
#include <hip/hip_runtime.h>
#include <stdint.h>

// ---------------- common types / helpers ----------------
typedef _Float16 f16x8 __attribute__((ext_vector_type(8)));
typedef _Float16 f16x4 __attribute__((ext_vector_type(4)));
typedef __fp16   fp16x2 __attribute__((ext_vector_type(2)));   // builtin cvt_pkrtz return type
typedef float f32x4  __attribute__((ext_vector_type(4)));
typedef float f32x16 __attribute__((ext_vector_type(16)));

__device__ __forceinline__ _Float16 f2h(float f){ return (_Float16)f; }

// async global->LDS, 16B per lane; LDS dest = wave-uniform base + lane*16
__device__ __forceinline__ void gl16(const void* g, void* l){
  __builtin_amdgcn_global_load_lds((const __attribute__((address_space(1))) void*)g,
                                   (__attribute__((address_space(3))) void*)l, 16, 0, 0);
}

// Problem constants
#define NB   32
#define NC   512
#define NH   8
#define ND   64
#define NN   1024

#define LOG2E 1.44269504f

// ---------------- prep kernels ----------------
__global__ __launch_bounds__(256) void wt_conv(const float* __restrict__ Wq,
                                               const float* __restrict__ Wk,
                                               const float* __restrict__ Wv,
                                               _Float16* __restrict__ Wt){
  int idx = blockIdx.x * 256 + threadIdx.x;          // 1536*512 = 786432 exact
  int sel = idx >> 18;                               // 262144 per matrix
  const float* W = (sel == 0) ? Wq : (sel == 1) ? Wk : Wv;
  Wt[idx] = f2h(W[idx & 262143]);
}

__global__ __launch_bounds__(256) void transpose_x(const float* __restrict__ x,
                                                   _Float16* __restrict__ xT){
  __shared__ float tile[32][33];
  int n0 = blockIdx.x * 32, c0 = blockIdx.y * 32, b = blockIdx.z;
  int t = threadIdx.x;
  int tn = t & 31, tc = t >> 5;                      // 8 c-rows per pass
#pragma unroll
  for (int k = 0; k < 4; k++)
    tile[tc + 8*k][tn] = x[(b*NC + c0 + tc + 8*k)*NN + n0 + tn];
  __syncthreads();
#pragma unroll
  for (int k = 0; k < 4; k++)
    xT[(b*NN + n0 + tc + 8*k)*NC + c0 + tn] = f2h(tile[tn][tc + 8*k]);
}

__global__ __launch_bounds__(256) void pos_conv(const float* __restrict__ rel_h,
                                                const float* __restrict__ rel_w,
                                                _Float16* __restrict__ pos_t){
  int idx = blockIdx.x * 256 + threadIdx.x;          // 8*1024*64 = 524288 exact
  int d = idx & 63, n = (idx >> 6) & 1023, h = idx >> 16;
  int ww = n >> 5, hh = n & 31;
  float v = rel_h[(h*ND + d)*32 + hh] + rel_w[(h*ND + d)*32 + ww];
  pos_t[idx] = f2h(v);
}

// ---------------- QKV projection GEMM (r12, gl16 staging) ----------------
#define TSTR 136     // epilogue tile stride in halves (128 + 8) -> 272B

__global__ __launch_bounds__(256) void proj_gemm(const _Float16* __restrict__ Wt,
                                                 const _Float16* __restrict__ xT,
                                                 const float* __restrict__ bq,
                                                 const float* __restrict__ bk,
                                                 const float* __restrict__ bv,
                                                 _Float16* __restrict__ q_ws,
                                                 _Float16* __restrict__ k_ws,
                                                 _Float16* __restrict__ v_ws){
  __shared__ _Float16 smem[17408];                   // 34816 B (As 8192 | Bs 8192; Ts reuse 17408)
  _Float16* As = smem;                               // [128][64] linear, source-swizzled
  _Float16* Bs = smem + 8192;                        // [128][64] linear, source-swizzled

  int mt = blockIdx.x;         // 0..11  (row tile of 1536; 8..11 = v)
  int nt = blockIdx.y;         // 0..7   (pixel tile of 1024)
  int b  = blockIdx.z;
  int t = threadIdx.x, lane = t & 63, w = t >> 6;
  int wm = w >> 1, wn = w & 1;
  int lr = lane & 15, lg = lane >> 4;

  f32x4 acc[4][4];
#pragma unroll
  for (int i = 0; i < 4; i++)
#pragma unroll
    for (int j = 0; j < 4; j++) acc[i][j] = (f32x4)0.f;

  const _Float16* Arow = Wt + mt * 128 * NC;
  const _Float16* Brow = xT + (b * NN + nt * 128) * NC;

  int s_r8 = lane >> 3;                              // staging: 8 rows per wave-segment
  int s_g  = lane & 7;

  for (int k0 = 0; k0 < NC; k0 += 64){
    __syncthreads();                                 // prev compute's LDS reads done
#pragma unroll
    for (int i = 0; i < 4; i++){
      int r0  = w*32 + i*8;
      int row = r0 + s_r8;
      int gx  = (s_g ^ (row & 7)) << 3;              // pre-swizzled global granule
      gl16(Arow + row*NC + k0 + gx, As + r0*64);
      gl16(Brow + row*NC + k0 + gx, Bs + r0*64);
    }
    __syncthreads();                                 // drains vmcnt -> tile visible
#pragma unroll
    for (int ks = 0; ks < 2; ks++){
      int xg = (((ks << 2) | lg) ^ (lr & 7)) << 3;   // row&7 == lr&7 (16-aligned tiles)
      f16x8 af[4], bfr[4];
#pragma unroll
      for (int mi = 0; mi < 4; mi++)
        af[mi] = *(f16x8*)(As + (wm*64 + mi*16 + lr)*64 + xg);
#pragma unroll
      for (int nj = 0; nj < 4; nj++)
        bfr[nj] = *(f16x8*)(Bs + (wn*64 + nj*16 + lr)*64 + xg);
      __builtin_amdgcn_s_setprio(1);
#pragma unroll
      for (int mi = 0; mi < 4; mi++)
#pragma unroll
        for (int nj = 0; nj < 4; nj++)
          acc[mi][nj] = __builtin_amdgcn_mfma_f32_16x16x32_f16(af[mi], bfr[nj], acc[mi][nj], 0, 0, 0);
      __builtin_amdgcn_s_setprio(0);
    }
  }
  __syncthreads();

  if (mt < 8){
    // q/k path: +bias, (q: *log2e), ->f16, LDS tile [pix][o_loc], coalesced store
    _Float16* Ts = smem;                              // 128*136 = 17408 halves
#pragma unroll
    for (int mi = 0; mi < 4; mi++){
      int o0 = wm*64 + mi*16 + 4*lg;
      int og = mt*128 + o0;
      int sel = og >> 9, oo = og & 511;
      const float* bias = (sel == 0) ? bq : bk;
      float sc = (sel == 0) ? LOG2E : 1.f;
      float b0 = bias[oo], b1 = bias[oo+1], b2 = bias[oo+2], b3 = bias[oo+3];
#pragma unroll
      for (int nj = 0; nj < 4; nj++){
        int pix = wn*64 + nj*16 + lr;
        f16x4 pk;
        pk[0] = f2h((acc[mi][nj][0] + b0) * sc);
        pk[1] = f2h((acc[mi][nj][1] + b1) * sc);
        pk[2] = f2h((acc[mi][nj][2] + b2) * sc);
        pk[3] = f2h((acc[mi][nj][3] + b3) * sc);
        *(f16x4*)(Ts + pix*TSTR + o0) = pk;
      }
    }
    __syncthreads();
#pragma unroll
    for (int i = 0; i < 8; i++){
      int lin = t + 256 * i;                          // 0..2047
      int c_o = lin & 15, pix = lin >> 4;
      f16x8 v = *(f16x8*)(Ts + pix*TSTR + c_o*8);
      int og = mt*128 + c_o*8;
      int sel = og >> 9, oo = og & 511;
      int head = oo >> 6, d = oo & 63;
      _Float16* dst = (sel == 0) ? q_ws : k_ws;
      *(f16x8*)(dst + (((b*NH + head)*NN) + nt*128 + pix)*ND + d) = v;
    }
  } else {
    // v path: +bias, ->f16, LDS tile [o_loc][pix], d-major store v_ws[b][h][d][n]
    _Float16* Ts2 = smem;                             // [128][TSTR]
#pragma unroll
    for (int mi = 0; mi < 4; mi++){
      int o0 = wm*64 + mi*16 + 4*lg;
      int vb = (mt - 8)*128 + o0;
      float b0 = bv[vb], b1 = bv[vb+1], b2 = bv[vb+2], b3 = bv[vb+3];
#pragma unroll
      for (int nj = 0; nj < 4; nj++){
        int pix = wn*64 + nj*16 + lr;
        Ts2[(o0+0)*TSTR + pix] = f2h(acc[mi][nj][0] + b0);
        Ts2[(o0+1)*TSTR + pix] = f2h(acc[mi][nj][1] + b1);
        Ts2[(o0+2)*TSTR + pix] = f2h(acc[mi][nj][2] + b2);
        Ts2[(o0+3)*TSTR + pix] = f2h(acc[mi][nj][3] + b3);
      }
    }
    __syncthreads();
#pragma unroll
    for (int i = 0; i < 8; i++){
      int lin = t + 256 * i;                          // 0..2047
      int pix8 = lin & 15, o_loc = lin >> 4;          // 16 pix-chunks x 128 o
      f16x8 v = *(f16x8*)(Ts2 + o_loc*TSTR + pix8*8);
      int vb = (mt - 8)*128 + o_loc;
      int head = vb >> 6, d = vb & 63;
      *(f16x8*)(v_ws + ((b*NH + head)*ND + d)*NN + nt*128 + pix8*8) = v;
    }
  }
}

// ---------------- fused attention: 32x32x16 MFMA, P entirely in registers ----------------
// Wave w owns q rows [w*32, w*32+32); lane's q-col = lane&31 (C col map, m74/m101-verified).
// S^T = mfma32(K_frag, Q_frag): lane holds 32 S-values of ONE q-row -> softmax lane-local.
// PV B-frag slot e of step s == sacc reg 8s+e (derived from verified C-row map); P packed
// in-register via cvt_pkrtz of adjacent regs. A(V)/B(P) share the k-map -> permutation-safe.
// LDS (halves): Kc[64][136] @0 | Vt[64][64] swz @8704; epilogue Ot f32 [128][65] aliases all.
#define KSTR 136
#define OSTR 65
#define OFF_VT 8704

__global__ __launch_bounds__(256) void attn_kernel(const _Float16* __restrict__ q_ws,
                                                   const _Float16* __restrict__ k_ws,
                                                   const _Float16* __restrict__ v_ws,
                                                   const _Float16* __restrict__ pos_t,
                                                   _Float16* __restrict__ o16,
                                                   float* __restrict__ red){
  __shared__ _Float16 smem[16640];                   // 33280 B (Ot epilogue is the max user)
  __shared__ float lnred[8];
  _Float16* Kc = smem;                               // [64][136]
  _Float16* Vt = smem + OFF_VT;                      // [64][64], XOR-swizzled (16B granule)

  // XCD-aware swizzle: 8 q-tiles sharing one (b,h)'s K/V -> same XCD L2
  int bid = blockIdx.x;                              // 0..2047
  int sid = (bid & 7) * 256 + (bid >> 3);
  int qt = sid & 7, h = (sid >> 3) & 7, b = sid >> 6;

  int t = threadIdx.x, lane = t & 63, w = t >> 6;
  int qc = lane & 31, hf = lane >> 5;                // q-col / lane-half
  int h4 = hf << 2;                                  // 4*hf

  const _Float16* qbh = q_ws + (b*NH + h) * NN * ND;
  const _Float16* kbh = k_ws + (b*NH + h) * NN * ND;
  const _Float16* vbh = v_ws + (b*NH + h) * ND * NN; // d-major
  const _Float16* pph = pos_t + h * NN * ND;

  union v8u { f16x4 v4[2]; f16x8 v8; };

  // Q+pos B-fragments in registers: slot e of kstep ks -> c = ks*16 + 8*(e>>2) + 4*hf + (e&3)
  f16x8 qreg[8];
  {
    int row = qt*128 + w*32 + qc;
#pragma unroll
    for (int ks = 0; ks < 8; ks++){
      int c = (ks & 3) * 16;
      const _Float16* src = (ks < 4) ? (qbh + row*ND + c) : (pph + row*ND + c);
      v8u u;
      u.v4[0] = *(const f16x4*)(src + h4);
      u.v4[1] = *(const f16x4*)(src + 8 + h4);
      qreg[ks] = u.v8;
    }
  }

  // all-ones A fragment for the l-accumulating MFMA (row map irrelevant: all ones)
  f16x8 ones;
#pragma unroll
  for (int e = 0; e < 8; e++) ones[e] = (_Float16)1.f;

  float m_r = -1e30f;
  f32x16 oacc[2];                                    // O^T tiles: rows d (C row map), col q=lane&31
  f32x16 lacc = (f32x16)0.f;                         // all rows equal = l[q], lane-local
  oacc[0] = (f32x16)0.f; oacc[1] = (f32x16)0.f;

  for (int n0 = 0; n0 < NN; n0 += 64){
    __syncthreads();                                 // prev tile's LDS reads done
    // stage Kc: row n -> [ k(64) | q(64) ]
#pragma unroll
    for (int i = 0; i < 4; i++){
      int lin = t + 256*i;                           // 0..1023
      int row = lin >> 4, c8 = lin & 15;
      const _Float16* src = (c8 < 8) ? (kbh + (n0 + row)*ND + c8*8)
                                     : (qbh + (n0 + row)*ND + (c8 - 8)*8);
      *(f16x8*)(Kc + row*KSTR + c8*8) = *(const f16x8*)src;
    }
    // stage Vt[d][kk] = V[n0+kk][d] from d-major v_ws, XOR-swizzled cols (16B granule)
#pragma unroll
    for (int i = 0; i < 2; i++){
      int lin = t + 256*i;                           // 0..511
      int d = lin >> 3, ch = lin & 7;
      *(f16x8*)(Vt + d*64 + ((ch*8) ^ ((d & 7) << 3))) = *(const f16x8*)(vbh + d*NN + n0 + ch*8);
    }
    __syncthreads();                                 // LDS visible

    // S^T = Kc . Qreg : 2 key-tiles of 32, K=128 over 8 ksteps of 16
    f32x16 sacc[2];
    sacc[0] = (f32x16)0.f; sacc[1] = (f32x16)0.f;
    __builtin_amdgcn_s_setprio(1);
#pragma unroll
    for (int ks = 0; ks < 8; ks++){
      int cb = ks*16 + h4;
#pragma unroll
      for (int kt = 0; kt < 2; kt++){
        const _Float16* kr = Kc + (kt*32 + qc)*KSTR + cb;
        v8u u;
        u.v4[0] = *(const f16x4*)(kr);
        u.v4[1] = *(const f16x4*)(kr + 8);
        sacc[kt] = __builtin_amdgcn_mfma_f32_32x32x16_f16(u.v8, qreg[ks], sacc[kt], 0, 0, 0);
      }
    }
    __builtin_amdgcn_s_setprio(0);

    // online softmax (exp2 domain): lane owns q-row qc entirely (32 in-lane + lane^32 half)
    {
      float mx = sacc[0][0];
#pragma unroll
      for (int r = 1; r < 16; r++) mx = fmaxf(mx, sacc[0][r]);
#pragma unroll
      for (int r = 0; r < 16; r++) mx = fmaxf(mx, sacc[1][r]);
      mx = fmaxf(mx, __shfl_xor(mx, 32));
      // defer-max: skip rescale while tile max within 11 (log2) of running max (P <= 2^11)
      if (!__all(mx - m_r <= 11.f)){
        float mn2 = fmaxf(m_r, mx);
        float cr = __builtin_exp2f(m_r - mn2);       // lane-local (q = col = lane&31)
        m_r = mn2;
        lacc *= cr;                                  // NO shuffles: q is the C column
        oacc[0] *= cr; oacc[1] *= cr;
      }
    }
    float mn = m_r;

    // exp+pack+PV per 16-key step: P B-frag slot e = exp2(sacc[s>>1][8*(s&1)+e] - mn)
    __builtin_amdgcn_s_setprio(1);
#pragma unroll
    for (int s = 0; s < 4; s++){
      int kt = s >> 1, rb = (s & 1) << 3;
      float p0 = __builtin_exp2f(sacc[kt][rb+0] - mn);
      float p1 = __builtin_exp2f(sacc[kt][rb+1] - mn);
      float p2 = __builtin_exp2f(sacc[kt][rb+2] - mn);
      float p3 = __builtin_exp2f(sacc[kt][rb+3] - mn);
      float p4 = __builtin_exp2f(sacc[kt][rb+4] - mn);
      float p5 = __builtin_exp2f(sacc[kt][rb+5] - mn);
      float p6 = __builtin_exp2f(sacc[kt][rb+6] - mn);
      float p7 = __builtin_exp2f(sacc[kt][rb+7] - mn);
      union { fp16x2 h2[4]; f16x8 v8; } pe;
      pe.h2[0] = __builtin_amdgcn_cvt_pkrtz(p0, p1);
      pe.h2[1] = __builtin_amdgcn_cvt_pkrtz(p2, p3);
      pe.h2[2] = __builtin_amdgcn_cvt_pkrtz(p4, p5);
      pe.h2[3] = __builtin_amdgcn_cvt_pkrtz(p6, p7);
      // V A-frags: slot e -> col 16s + 8*(e>>2) + 4*hf + (e&3); swizzled granule reads
      f16x8 vf[2];
#pragma unroll
      for (int dt = 0; dt < 2; dt++){
        int row = dt*32 + qc;
        int sw = (row & 7) << 3;
        v8u u;
        u.v4[0] = *(const f16x4*)(Vt + row*64 + ((16*s) ^ sw) + h4);
        u.v4[1] = *(const f16x4*)(Vt + row*64 + ((16*s + 8) ^ sw) + h4);
        vf[dt] = u.v8;
      }
      lacc = __builtin_amdgcn_mfma_f32_32x32x16_f16(ones, pe.v8, lacc, 0, 0, 0);
      oacc[0] = __builtin_amdgcn_mfma_f32_32x32x16_f16(vf[0], pe.v8, oacc[0], 0, 0, 0);
      oacc[1] = __builtin_amdgcn_mfma_f32_32x32x16_f16(vf[1], pe.v8, oacc[1], 0, 0, 0);
    }
    __builtin_amdgcn_s_setprio(0);
  }

  // ---------------- epilogue: lane-local 1/l, LDS transpose, coalesced f16 store ----------------
  float s_ln = 0.f, q_ln = 0.f;
  __syncthreads();                                   // all PV LDS reads done
  float* Ot = (float*)smem;                          // [128][OSTR] fp32 = 33280 B
  {
    float inv = 1.f / lacc[0];                       // l[q], lane-local: NO shfl
    int qrow = w*32 + qc;
#pragma unroll
    for (int dt = 0; dt < 2; dt++){
#pragma unroll
      for (int r = 0; r < 16; r++){
        int d = dt*32 + (r & 3) + ((r >> 2) << 3) + h4;   // verified C row map
        float val = oacc[dt][r] * inv;
        s_ln += val; q_ln += val*val;
        Ot[qrow*OSTR + d] = val;
      }
    }
  }
  __syncthreads();

  // coalesced f16 store: o16[b][h*64+d][qt*128 + j]  (16B per thread-iter)
#pragma unroll
  for (int i = 0; i < 4; i++){
    int lin = t + 256*i;                             // 0..1023
    int d = lin >> 4, jc = lin & 15;
    f16x8 v;
#pragma unroll
    for (int e = 0; e < 8; e++) v[e] = f2h(Ot[(jc*8 + e)*OSTR + d]);
    *(f16x8*)(o16 + (b*NC + h*ND + d)*NN + qt*128 + jc*8) = v;
  }

  // LN partial reduce: block sum of val and val^2 -> red[(b*64 + h*8 + qt)*2 + {0,1}]
#pragma unroll
  for (int off = 1; off < 64; off <<= 1){
    s_ln += __shfl_xor(s_ln, off);
    q_ln += __shfl_xor(q_ln, off);
  }
  if (lane == 0){ lnred[w*2] = s_ln; lnred[w*2 + 1] = q_ln; }
  __syncthreads();
  if (t == 0){
    int idx = ((b*NH + h)*8 + qt)*2;
    red[idx]     = lnred[0] + lnred[2] + lnred[4] + lnred[6];
    red[idx + 1] = lnred[1] + lnred[3] + lnred[5] + lnred[7];
  }
}

// ---------------- LayerNorm stats + apply ----------------
__global__ void ln_stats(const float* __restrict__ red, float* __restrict__ stats){
  int b = threadIdx.x;
  if (b < 32){
    float s = 0.f, sq = 0.f;
    for (int j = 0; j < 64; j++){ s += red[(b*64 + j)*2]; sq += red[(b*64 + j)*2 + 1]; }
    float mu  = s * (1.f / 524288.f);
    float var = sq * (1.f / 524288.f) - mu*mu;
    stats[b*2] = mu;
    stats[b*2 + 1] = rsqrtf(var + 1e-5f);
  }
}

__global__ __launch_bounds__(256) void ln_apply(const float* __restrict__ x,
                                                const _Float16* __restrict__ o16,
                                                const float* __restrict__ lw,
                                                const float* __restrict__ lb,
                                                const float* __restrict__ stats,
                                                float* __restrict__ out){
  int tid = blockIdx.x*256 + threadIdx.x;
  for (int i8 = tid; i8 < 2097152; i8 += 524288){    // 8 elements per iter
    int b = i8 >> 16;                                // 65536 groups of 8 per batch
    int r8 = i8 & 65535;
    float mu = stats[b*2], rs = stats[b*2 + 1];
    f16x8 o = *(const f16x8*)(o16 + (size_t)i8*8);
    float4 x0 = ((const float4*)x)[i8*2],  x1 = ((const float4*)x)[i8*2 + 1];
    float4 w0 = ((const float4*)lw)[r8*2], w1 = ((const float4*)lw)[r8*2 + 1];
    float4 b0 = ((const float4*)lb)[r8*2], b1 = ((const float4*)lb)[r8*2 + 1];
    float4 r0, r1;
    r0.x = ((float)o[0] - mu)*rs*w0.x + b0.x + x0.x;
    r0.y = ((float)o[1] - mu)*rs*w0.y + b0.y + x0.y;
    r0.z = ((float)o[2] - mu)*rs*w0.z + b0.z + x0.z;
    r0.w = ((float)o[3] - mu)*rs*w0.w + b0.w + x0.w;
    r1.x = ((float)o[4] - mu)*rs*w1.x + b1.x + x1.x;
    r1.y = ((float)o[5] - mu)*rs*w1.y + b1.y + x1.y;
    r1.z = ((float)o[6] - mu)*rs*w1.z + b1.z + x1.z;
    r1.w = ((float)o[7] - mu)*rs*w1.w + b1.w + x1.w;
    ((float4*)out)[i8*2]     = r0;
    ((float4*)out)[i8*2 + 1] = r1;
  }
}

// ---------------- launch ----------------
extern "C" void kernel_launch(void* const* d_in, const int* in_sizes, int n_in,
                              void* d_out, int out_size, void* d_ws, size_t ws_size,
                              hipStream_t stream){
  (void)in_sizes; (void)n_in; (void)out_size; (void)ws_size;
  const float* x    = (const float*)d_in[0];
  const float* Wq   = (const float*)d_in[1];
  const float* bq   = (const float*)d_in[2];
  const float* Wk   = (const float*)d_in[3];
  const float* bk   = (const float*)d_in[4];
  const float* Wv   = (const float*)d_in[5];
  const float* bv   = (const float*)d_in[6];
  const float* relh = (const float*)d_in[7];
  const float* relw = (const float*)d_in[8];
  const float* lnw  = (const float*)d_in[9];
  const float* lnb  = (const float*)d_in[10];
  float* out = (float*)d_out;
  char* ws = (char*)d_ws;

  _Float16* q_ws  = (_Float16*)(ws);
  _Float16* k_ws  = (_Float16*)(ws + 33554432);
  _Float16* v_ws  = (_Float16*)(ws + 67108864);   // d-major [b][h][d][n]
  _Float16* xT    = (_Float16*)(ws + 100663296);  // 32 MB; dead after proj_gemm -> reused as o16
  _Float16* Wt    = (_Float16*)(ws + 134217728);
  _Float16* pos_t = (_Float16*)(ws + 135790592);
  float* red   = (float*)(ws + 136839168);        // 2048*2 floats
  float* stats = red + 4096;
  _Float16* o16 = xT;                             // attn f16 output aliases xT

  wt_conv    <<<3072, 256, 0, stream>>>(Wq, Wk, Wv, Wt);
  transpose_x<<<dim3(32, 16, 32), 256, 0, stream>>>(x, xT);
  pos_conv   <<<2048, 256, 0, stream>>>(relh, relw, pos_t);
  proj_gemm  <<<dim3(12, 8, 32), 256, 0, stream>>>(Wt, xT, bq, bk, bv, q_ws, k_ws, v_ws);
  attn_kernel<<<2048, 256, 0, stream>>>(q_ws, k_ws, v_ws, pos_t, o16, red);
  ln_stats   <<<1, 64, 0, stream>>>(red, stats);
  ln_apply   <<<2048, 256, 0, stream>>>(x, o16, lnw, lnb, stats, out);
}

// Round 17
// 291.240 us; speedup vs baseline: 1.1393x; 1.1393x over previous
//
#include <hip/hip_runtime.h>
#include <stdint.h>

// ---------------- common types / helpers ----------------
typedef _Float16 f16x8 __attribute__((ext_vector_type(8)));
typedef _Float16 f16x4 __attribute__((ext_vector_type(4)));
typedef __fp16   fp16x2 __attribute__((ext_vector_type(2)));   // builtin cvt_pkrtz return type
typedef float f32x4  __attribute__((ext_vector_type(4)));

__device__ __forceinline__ _Float16 f2h(float f){ return (_Float16)f; }

// async global->LDS, 16B per lane; LDS dest = wave-uniform base + lane*16
__device__ __forceinline__ void gl16(const void* g, void* l){
  __builtin_amdgcn_global_load_lds((const __attribute__((address_space(1))) void*)g,
                                   (__attribute__((address_space(3))) void*)l, 16, 0, 0);
}

// Problem constants
#define NB   32
#define NC   512
#define NH   8
#define ND   64
#define NN   1024

#define LOG2E 1.44269504f

// ---------------- prep kernels ----------------
__global__ __launch_bounds__(256) void wt_conv(const float* __restrict__ Wq,
                                               const float* __restrict__ Wk,
                                               const float* __restrict__ Wv,
                                               _Float16* __restrict__ Wt){
  int idx = blockIdx.x * 256 + threadIdx.x;          // 1536*512 = 786432 exact
  int sel = idx >> 18;                               // 262144 per matrix
  const float* W = (sel == 0) ? Wq : (sel == 1) ? Wk : Wv;
  Wt[idx] = f2h(W[idx & 262143]);
}

__global__ __launch_bounds__(256) void transpose_x(const float* __restrict__ x,
                                                   _Float16* __restrict__ xT){
  __shared__ float tile[32][33];
  int n0 = blockIdx.x * 32, c0 = blockIdx.y * 32, b = blockIdx.z;
  int t = threadIdx.x;
  int tn = t & 31, tc = t >> 5;                      // 8 c-rows per pass
#pragma unroll
  for (int k = 0; k < 4; k++)
    tile[tc + 8*k][tn] = x[(b*NC + c0 + tc + 8*k)*NN + n0 + tn];
  __syncthreads();
#pragma unroll
  for (int k = 0; k < 4; k++)
    xT[(b*NN + n0 + tc + 8*k)*NC + c0 + tn] = f2h(tile[tn][tc + 8*k]);
}

__global__ __launch_bounds__(256) void pos_conv(const float* __restrict__ rel_h,
                                                const float* __restrict__ rel_w,
                                                _Float16* __restrict__ pos_t){
  int idx = blockIdx.x * 256 + threadIdx.x;          // 8*1024*64 = 524288 exact
  int d = idx & 63, n = (idx >> 6) & 1023, h = idx >> 16;
  int ww = n >> 5, hh = n & 31;
  float v = rel_h[(h*ND + d)*32 + hh] + rel_w[(h*ND + d)*32 + ww];
  pos_t[idx] = f2h(v);
}

// ---------------- QKV projection GEMM (gl16 staging) ----------------
#define TSTR 136     // epilogue tile stride in halves (128 + 8) -> 272B

__global__ __launch_bounds__(256) void proj_gemm(const _Float16* __restrict__ Wt,
                                                 const _Float16* __restrict__ xT,
                                                 const float* __restrict__ bq,
                                                 const float* __restrict__ bk,
                                                 const float* __restrict__ bv,
                                                 _Float16* __restrict__ q_ws,
                                                 _Float16* __restrict__ k_ws,
                                                 _Float16* __restrict__ v_ws){
  __shared__ _Float16 smem[17408];                   // 34816 B (As 8192 | Bs 8192; Ts reuse 17408)
  _Float16* As = smem;                               // [128][64] linear, source-swizzled
  _Float16* Bs = smem + 8192;                        // [128][64] linear, source-swizzled

  int mt = blockIdx.x;         // 0..11  (row tile of 1536; 8..11 = v)
  int nt = blockIdx.y;         // 0..7   (pixel tile of 1024)
  int b  = blockIdx.z;
  int t = threadIdx.x, lane = t & 63, w = t >> 6;
  int wm = w >> 1, wn = w & 1;
  int lr = lane & 15, lg = lane >> 4;

  f32x4 acc[4][4];
#pragma unroll
  for (int i = 0; i < 4; i++)
#pragma unroll
    for (int j = 0; j < 4; j++) acc[i][j] = (f32x4)0.f;

  const _Float16* Arow = Wt + mt * 128 * NC;
  const _Float16* Brow = xT + (b * NN + nt * 128) * NC;

  int s_r8 = lane >> 3;                              // staging: 8 rows per wave-segment
  int s_g  = lane & 7;

  for (int k0 = 0; k0 < NC; k0 += 64){
    __syncthreads();                                 // prev compute's LDS reads done
#pragma unroll
    for (int i = 0; i < 4; i++){
      int r0  = w*32 + i*8;
      int row = r0 + s_r8;
      int gx  = (s_g ^ (row & 7)) << 3;              // pre-swizzled global granule
      gl16(Arow + row*NC + k0 + gx, As + r0*64);
      gl16(Brow + row*NC + k0 + gx, Bs + r0*64);
    }
    __syncthreads();                                 // drains vmcnt -> tile visible
#pragma unroll
    for (int ks = 0; ks < 2; ks++){
      int xg = (((ks << 2) | lg) ^ (lr & 7)) << 3;   // row&7 == lr&7 (16-aligned tiles)
      f16x8 af[4], bfr[4];
#pragma unroll
      for (int mi = 0; mi < 4; mi++)
        af[mi] = *(f16x8*)(As + (wm*64 + mi*16 + lr)*64 + xg);
#pragma unroll
      for (int nj = 0; nj < 4; nj++)
        bfr[nj] = *(f16x8*)(Bs + (wn*64 + nj*16 + lr)*64 + xg);
      __builtin_amdgcn_s_setprio(1);
#pragma unroll
      for (int mi = 0; mi < 4; mi++)
#pragma unroll
        for (int nj = 0; nj < 4; nj++)
          acc[mi][nj] = __builtin_amdgcn_mfma_f32_16x16x32_f16(af[mi], bfr[nj], acc[mi][nj], 0, 0, 0);
      __builtin_amdgcn_s_setprio(0);
    }
  }
  __syncthreads();

  if (mt < 8){
    // q/k path: +bias, (q: *log2e), ->f16, LDS tile [pix][o_loc], coalesced store
    _Float16* Ts = smem;                              // 128*136 = 17408 halves
#pragma unroll
    for (int mi = 0; mi < 4; mi++){
      int o0 = wm*64 + mi*16 + 4*lg;
      int og = mt*128 + o0;
      int sel = og >> 9, oo = og & 511;
      const float* bias = (sel == 0) ? bq : bk;
      float sc = (sel == 0) ? LOG2E : 1.f;
      float b0 = bias[oo], b1 = bias[oo+1], b2 = bias[oo+2], b3 = bias[oo+3];
#pragma unroll
      for (int nj = 0; nj < 4; nj++){
        int pix = wn*64 + nj*16 + lr;
        f16x4 pk;
        pk[0] = f2h((acc[mi][nj][0] + b0) * sc);
        pk[1] = f2h((acc[mi][nj][1] + b1) * sc);
        pk[2] = f2h((acc[mi][nj][2] + b2) * sc);
        pk[3] = f2h((acc[mi][nj][3] + b3) * sc);
        *(f16x4*)(Ts + pix*TSTR + o0) = pk;
      }
    }
    __syncthreads();
#pragma unroll
    for (int i = 0; i < 8; i++){
      int lin = t + 256 * i;                          // 0..2047
      int c_o = lin & 15, pix = lin >> 4;
      f16x8 v = *(f16x8*)(Ts + pix*TSTR + c_o*8);
      int og = mt*128 + c_o*8;
      int sel = og >> 9, oo = og & 511;
      int head = oo >> 6, d = oo & 63;
      _Float16* dst = (sel == 0) ? q_ws : k_ws;
      *(f16x8*)(dst + (((b*NH + head)*NN) + nt*128 + pix)*ND + d) = v;
    }
  } else {
    // v path: +bias, ->f16, LDS tile [o_loc][pix], d-major store v_ws[b][h][d][n]
    _Float16* Ts2 = smem;                             // [128][TSTR]
#pragma unroll
    for (int mi = 0; mi < 4; mi++){
      int o0 = wm*64 + mi*16 + 4*lg;
      int vb = (mt - 8)*128 + o0;
      float b0 = bv[vb], b1 = bv[vb+1], b2 = bv[vb+2], b3 = bv[vb+3];
#pragma unroll
      for (int nj = 0; nj < 4; nj++){
        int pix = wn*64 + nj*16 + lr;
        Ts2[(o0+0)*TSTR + pix] = f2h(acc[mi][nj][0] + b0);
        Ts2[(o0+1)*TSTR + pix] = f2h(acc[mi][nj][1] + b1);
        Ts2[(o0+2)*TSTR + pix] = f2h(acc[mi][nj][2] + b2);
        Ts2[(o0+3)*TSTR + pix] = f2h(acc[mi][nj][3] + b3);
      }
    }
    __syncthreads();
#pragma unroll
    for (int i = 0; i < 8; i++){
      int lin = t + 256 * i;                          // 0..2047
      int pix8 = lin & 15, o_loc = lin >> 4;          // 16 pix-chunks x 128 o
      f16x8 v = *(f16x8*)(Ts2 + o_loc*TSTR + pix8*8);
      int vb = (mt - 8)*128 + o_loc;
      int head = vb >> 6, d = vb & 63;
      *(f16x8*)(v_ws + ((b*NH + head)*ND + d)*NN + nt*128 + pix8*8) = v;
    }
  }
}

// ---------------- fused attention (best measured: r11 structure + f16 output) ----------------
// 4 waves x 32 q-rows, 2 barriers/tile, P in own LDS region, d-major swizzled Vt,
// exp2 softmax, defer-max, cvt_pkrtz, setprio, l via MFMA-with-ones.
// Output stored as f16 (into dead xT region) — halves attn write + ln read bytes.
// LDS (halves): Kc[64][136] @0 | Vt[64][64] swz @8704 | P[128][72] @12800 = 44032 B -> 3 blocks/CU.
#define KSTR 136
#define PSTR 72
#define OSTR 65
#define OFF_VT 8704
#define OFF_P  12800

__global__ __launch_bounds__(256, 3) void attn_kernel(const _Float16* __restrict__ q_ws,
                                                      const _Float16* __restrict__ k_ws,
                                                      const _Float16* __restrict__ v_ws,
                                                      const _Float16* __restrict__ pos_t,
                                                      _Float16* __restrict__ o16,
                                                      float* __restrict__ red){
  __shared__ _Float16 smem[22016];                   // 44032 B
  __shared__ float lnred[8];
  _Float16* Kc = smem;                               // [64][136]
  _Float16* Vt = smem + OFF_VT;                      // [64][64], XOR-swizzled (16B granule)
  _Float16* Pl = smem + OFF_P;                       // [128][72]

  // XCD-aware swizzle: 8 q-tiles sharing one (b,h)'s K/V -> same XCD L2
  int bid = blockIdx.x;                              // 0..2047
  int sid = (bid & 7) * 256 + (bid >> 3);
  int qt = sid & 7, h = (sid >> 3) & 7, b = sid >> 6;

  int t = threadIdx.x, lane = t & 63, w = t >> 6;
  int lr = lane & 15, lg = lane >> 4;

  const _Float16* qbh = q_ws + (b*NH + h) * NN * ND;
  const _Float16* kbh = k_ws + (b*NH + h) * NN * ND;
  const _Float16* vbh = v_ws + (b*NH + h) * ND * NN; // d-major
  const _Float16* pph = pos_t + h * NN * ND;

  // Q+pos fragments in registers (q pre-scaled by log2e in proj_gemm)
  f16x8 qreg[2][4];
#pragma unroll
  for (int qi = 0; qi < 2; qi++){
    int row = qt*128 + w*32 + qi*16 + lr;
#pragma unroll
    for (int ks = 0; ks < 4; ks++){
      const _Float16* src = (ks < 2) ? (qbh + row*ND + ks*32 + lg*8)
                                     : (pph + row*ND + (ks-2)*32 + lg*8);
      qreg[qi][ks] = *(const f16x8*)src;
    }
  }

  // all-ones B fragment for the l-accumulating MFMA
  f16x8 ones;
#pragma unroll
  for (int e = 0; e < 8; e++) ones[e] = (_Float16)1.f;

  float m_r[2];
  f32x4 oacc[2][4];                                  // C layout: row q=4lg+r, col d=dj*16+lr
  f32x4 lacc[2];                                     // same C layout: lacc[qi][r] = l for q-row 4lg+r
#pragma unroll
  for (int qi = 0; qi < 2; qi++){ m_r[qi] = -1e30f; lacc[qi] = (f32x4)0.f; }
#pragma unroll
  for (int qi = 0; qi < 2; qi++)
#pragma unroll
    for (int dj = 0; dj < 4; dj++) oacc[qi][dj] = (f32x4)0.f;

  for (int n0 = 0; n0 < NN; n0 += 64){
    __syncthreads();                                 // prev tile's LDS reads done
    // stage Kc: row n -> [ k(64) | q(64) ]
#pragma unroll
    for (int i = 0; i < 4; i++){
      int lin = t + 256*i;                           // 0..1023
      int row = lin >> 4, c8 = lin & 15;
      const _Float16* src = (c8 < 8) ? (kbh + (n0 + row)*ND + c8*8)
                                     : (qbh + (n0 + row)*ND + (c8 - 8)*8);
      *(f16x8*)(Kc + row*KSTR + c8*8) = *(const f16x8*)src;
    }
    // stage Vt[d][kk] = V[n0+kk][d] from d-major v_ws, XOR-swizzled cols (16B granule)
#pragma unroll
    for (int i = 0; i < 2; i++){
      int lin = t + 256*i;                           // 0..511
      int d = lin >> 3, ch = lin & 7;
      *(f16x8*)(Vt + d*64 + ((ch*8) ^ ((d & 7) << 3))) = *(const f16x8*)(vbh + d*NN + n0 + ch*8);
    }
    __syncthreads();                                 // LDS visible

    // S^T = Kc . Qreg : sacc[kt][qi], row = key = kt*16+4lg+r, col = q = lr
    f32x4 sacc[4][2];
#pragma unroll
    for (int kt = 0; kt < 4; kt++)
#pragma unroll
      for (int qi = 0; qi < 2; qi++) sacc[kt][qi] = (f32x4)0.f;
    __builtin_amdgcn_s_setprio(1);
#pragma unroll
    for (int ks = 0; ks < 4; ks++){
      f16x8 kf[4];
#pragma unroll
      for (int kt = 0; kt < 4; kt++)
        kf[kt] = *(f16x8*)(Kc + (kt*16 + lr)*KSTR + ks*32 + lg*8);
#pragma unroll
      for (int kt = 0; kt < 4; kt++)
#pragma unroll
        for (int qi = 0; qi < 2; qi++)
          sacc[kt][qi] = __builtin_amdgcn_mfma_f32_16x16x32_f16(kf[kt], qreg[qi][ks], sacc[kt][qi], 0, 0, 0);
    }
    __builtin_amdgcn_s_setprio(0);

    // online softmax (exp2 domain): lane owns q=lr; l via MFMA below
#pragma unroll
    for (int qi = 0; qi < 2; qi++){
      float m0 = fmaxf(fmaxf(sacc[0][qi][0], sacc[0][qi][1]), fmaxf(sacc[0][qi][2], sacc[0][qi][3]));
      float m1 = fmaxf(fmaxf(sacc[1][qi][0], sacc[1][qi][1]), fmaxf(sacc[1][qi][2], sacc[1][qi][3]));
      float m2 = fmaxf(fmaxf(sacc[2][qi][0], sacc[2][qi][1]), fmaxf(sacc[2][qi][2], sacc[2][qi][3]));
      float m3 = fmaxf(fmaxf(sacc[3][qi][0], sacc[3][qi][1]), fmaxf(sacc[3][qi][2], sacc[3][qi][3]));
      float mx = fmaxf(fmaxf(m0, m1), fmaxf(m2, m3));
      mx = fmaxf(mx, __shfl_xor(mx, 16));
      mx = fmaxf(mx, __shfl_xor(mx, 32));
      // defer-max: skip rescale while tile max within 11 (log2) of running max (P <= 2^11, f16-safe)
      if (!__all(mx - m_r[qi] <= 11.f)){
        float mn2 = fmaxf(m_r[qi], mx);
        float cr = __builtin_exp2f(m_r[qi] - mn2);   // at q=lr
        m_r[qi] = mn2;
#pragma unroll
        for (int r = 0; r < 4; r++){
          float crow = __shfl(cr, 4*lg + r);         // broadcast to q=4lg+r (acc layout)
          lacc[qi][r] *= crow;
#pragma unroll
          for (int dj = 0; dj < 4; dj++) oacc[qi][dj][r] *= crow;
        }
      }
      float mn = m_r[qi];
#pragma unroll
      for (int kt = 0; kt < 4; kt++){
        float p0 = __builtin_exp2f(sacc[kt][qi][0] - mn);
        float p1 = __builtin_exp2f(sacc[kt][qi][1] - mn);
        float p2 = __builtin_exp2f(sacc[kt][qi][2] - mn);
        float p3 = __builtin_exp2f(sacc[kt][qi][3] - mn);
        union { fp16x2 h2[2]; uint2 u2; } pu;
        pu.h2[0] = __builtin_amdgcn_cvt_pkrtz(p0, p1);
        pu.h2[1] = __builtin_amdgcn_cvt_pkrtz(p2, p3);
        // P[q][k]: row = w*32+qi*16+lr, k = kt*16 + 4lg (+0..3)
        *(uint2*)(Pl + (w*32 + qi*16 + lr)*PSTR + kt*16 + lg*4) = pu.u2;
      }
    }

    // PV + l: wave-private P rows -> no barrier (lgkm dependency only)
    __builtin_amdgcn_s_setprio(1);
#pragma unroll
    for (int ks = 0; ks < 2; ks++){
      f16x8 pf[2], vf[4];
#pragma unroll
      for (int qi = 0; qi < 2; qi++)
        pf[qi] = *(f16x8*)(Pl + (w*32 + qi*16 + lr)*PSTR + ks*32 + lg*8);
#pragma unroll
      for (int dj = 0; dj < 4; dj++){
        int row = dj*16 + lr;
        vf[dj] = *(f16x8*)(Vt + row*64 + ((ks*32 + lg*8) ^ ((row & 7) << 3)));
      }
#pragma unroll
      for (int qi = 0; qi < 2; qi++){
        lacc[qi] = __builtin_amdgcn_mfma_f32_16x16x32_f16(pf[qi], ones, lacc[qi], 0, 0, 0);
#pragma unroll
        for (int dj = 0; dj < 4; dj++)
          oacc[qi][dj] = __builtin_amdgcn_mfma_f32_16x16x32_f16(pf[qi], vf[dj], oacc[qi][dj], 0, 0, 0);
      }
    }
    __builtin_amdgcn_s_setprio(0);
  }

  // ---------------- epilogue: shfl-free normalize, LDS transpose, coalesced f16 store ----------------
  float s_ln = 0.f, q_ln = 0.f;
  __syncthreads();                                   // all PV LDS reads done
  float* Ot = (float*)smem;                          // [128][OSTR] fp32 = 33280 B (fits 44032)
#pragma unroll
  for (int qi = 0; qi < 2; qi++){
#pragma unroll
    for (int r = 0; r < 4; r++){
      float invr = 1.f / lacc[qi][r];                // l in acc layout: NO shfl
#pragma unroll
      for (int dj = 0; dj < 4; dj++){
        float val = oacc[qi][dj][r] * invr;
        s_ln += val; q_ln += val*val;
        Ot[(w*32 + qi*16 + 4*lg + r)*OSTR + dj*16 + lr] = val;
      }
    }
  }
  __syncthreads();

  // coalesced f16 store: o16[b][h*64+d][qt*128 + j]  (16B per thread-iter)
#pragma unroll
  for (int i = 0; i < 4; i++){
    int lin = t + 256*i;                             // 0..1023
    int d = lin >> 4, jc = lin & 15;
    f16x8 v;
#pragma unroll
    for (int e = 0; e < 8; e++) v[e] = f2h(Ot[(jc*8 + e)*OSTR + d]);
    *(f16x8*)(o16 + (b*NC + h*ND + d)*NN + qt*128 + jc*8) = v;
  }

  // LN partial reduce: block sum of val and val^2 -> red[(b*64 + h*8 + qt)*2 + {0,1}]
#pragma unroll
  for (int off = 1; off < 64; off <<= 1){
    s_ln += __shfl_xor(s_ln, off);
    q_ln += __shfl_xor(q_ln, off);
  }
  if (lane == 0){ lnred[w*2] = s_ln; lnred[w*2 + 1] = q_ln; }
  __syncthreads();
  if (t == 0){
    int idx = ((b*NH + h)*8 + qt)*2;
    red[idx]     = lnred[0] + lnred[2] + lnred[4] + lnred[6];
    red[idx + 1] = lnred[1] + lnred[3] + lnred[5] + lnred[7];
  }
}

// ---------------- LayerNorm stats + apply ----------------
__global__ void ln_stats(const float* __restrict__ red, float* __restrict__ stats){
  int b = threadIdx.x;
  if (b < 32){
    float s = 0.f, sq = 0.f;
    for (int j = 0; j < 64; j++){ s += red[(b*64 + j)*2]; sq += red[(b*64 + j)*2 + 1]; }
    float mu  = s * (1.f / 524288.f);
    float var = sq * (1.f / 524288.f) - mu*mu;
    stats[b*2] = mu;
    stats[b*2 + 1] = rsqrtf(var + 1e-5f);
  }
}

__global__ __launch_bounds__(256) void ln_apply(const float* __restrict__ x,
                                                const _Float16* __restrict__ o16,
                                                const float* __restrict__ lw,
                                                const float* __restrict__ lb,
                                                const float* __restrict__ stats,
                                                float* __restrict__ out){
  int tid = blockIdx.x*256 + threadIdx.x;
  for (int i8 = tid; i8 < 2097152; i8 += 524288){    // 8 elements per iter
    int b = i8 >> 16;                                // 65536 groups of 8 per batch
    int r8 = i8 & 65535;
    float mu = stats[b*2], rs = stats[b*2 + 1];
    f16x8 o = *(const f16x8*)(o16 + (size_t)i8*8);
    float4 x0 = ((const float4*)x)[i8*2],  x1 = ((const float4*)x)[i8*2 + 1];
    float4 w0 = ((const float4*)lw)[r8*2], w1 = ((const float4*)lw)[r8*2 + 1];
    float4 b0 = ((const float4*)lb)[r8*2], b1 = ((const float4*)lb)[r8*2 + 1];
    float4 r0, r1;
    r0.x = ((float)o[0] - mu)*rs*w0.x + b0.x + x0.x;
    r0.y = ((float)o[1] - mu)*rs*w0.y + b0.y + x0.y;
    r0.z = ((float)o[2] - mu)*rs*w0.z + b0.z + x0.z;
    r0.w = ((float)o[3] - mu)*rs*w0.w + b0.w + x0.w;
    r1.x = ((float)o[4] - mu)*rs*w1.x + b1.x + x1.x;
    r1.y = ((float)o[5] - mu)*rs*w1.y + b1.y + x1.y;
    r1.z = ((float)o[6] - mu)*rs*w1.z + b1.z + x1.z;
    r1.w = ((float)o[7] - mu)*rs*w1.w + b1.w + x1.w;
    ((float4*)out)[i8*2]     = r0;
    ((float4*)out)[i8*2 + 1] = r1;
  }
}

// ---------------- launch ----------------
extern "C" void kernel_launch(void* const* d_in, const int* in_sizes, int n_in,
                              void* d_out, int out_size, void* d_ws, size_t ws_size,
                              hipStream_t stream){
  (void)in_sizes; (void)n_in; (void)out_size; (void)ws_size;
  const float* x    = (const float*)d_in[0];
  const float* Wq   = (const float*)d_in[1];
  const float* bq   = (const float*)d_in[2];
  const float* Wk   = (const float*)d_in[3];
  const float* bk   = (const float*)d_in[4];
  const float* Wv   = (const float*)d_in[5];
  const float* bv   = (const float*)d_in[6];
  const float* relh = (const float*)d_in[7];
  const float* relw = (const float*)d_in[8];
  const float* lnw  = (const float*)d_in[9];
  const float* lnb  = (const float*)d_in[10];
  float* out = (float*)d_out;
  char* ws = (char*)d_ws;

  _Float16* q_ws  = (_Float16*)(ws);
  _Float16* k_ws  = (_Float16*)(ws + 33554432);
  _Float16* v_ws  = (_Float16*)(ws + 67108864);   // d-major [b][h][d][n]
  _Float16* xT    = (_Float16*)(ws + 100663296);  // 32 MB; dead after proj_gemm -> reused as o16
  _Float16* Wt    = (_Float16*)(ws + 134217728);
  _Float16* pos_t = (_Float16*)(ws + 135790592);
  float* red   = (float*)(ws + 136839168);        // 2048*2 floats
  float* stats = red + 4096;
  _Float16* o16 = xT;                             // attn f16 output aliases xT

  wt_conv    <<<3072, 256, 0, stream>>>(Wq, Wk, Wv, Wt);
  transpose_x<<<dim3(32, 16, 32), 256, 0, stream>>>(x, xT);
  pos_conv   <<<2048, 256, 0, stream>>>(relh, relw, pos_t);
  proj_gemm  <<<dim3(12, 8, 32), 256, 0, stream>>>(Wt, xT, bq, bk, bv, q_ws, k_ws, v_ws);
  attn_kernel<<<2048, 256, 0, stream>>>(q_ws, k_ws, v_ws, pos_t, o16, red);
  ln_stats   <<<1, 64, 0, stream>>>(red, stats);
  ln_apply   <<<2048, 256, 0, stream>>>(x, o16, lnw, lnb, stats, out);
}